// Round 1
// baseline (451.104 us; speedup 1.0000x reference)
//
#include <hip/hip_runtime.h>
#include <math.h>

#define V 50257
#define E 1024
#define H 1024
#define L 512

// d_out offsets (floats): [log_probs V][h_new H][attn_weights L]
#define OUT_LP 0
#define OUT_H  50257
#define OUT_AW 51281

// ws offsets (floats)
#define WS_S    0       // 512 attn scores
#define WS_W    512     // 512 attn weights
#define WS_X    1024    // 2048 x = [embedded, attn_applied]
#define WS_GH   3072    // 3072
#define WS_GI   6144    // 3072
#define WS_HN   9216    // 1024 h_new
#define WS_BMAX 10240   // 2048 per-block maxes
#define WS_SUM  12288
#define WS_MAX  12289

// K1: attention scores (waves 0..511) + gh = h @ W_hh^T + b_hh (waves 512..3583)
__global__ void k1_scores_gh(const int* __restrict__ input,
                             const float* __restrict__ hidden,
                             const float* __restrict__ emb_table,
                             const float* __restrict__ attn_W,
                             const float* __restrict__ attn_b,
                             const float* __restrict__ W_hh,
                             const float* __restrict__ b_hh,
                             float* __restrict__ ws) {
    int wave = (blockIdx.x * blockDim.x + threadIdx.x) >> 6;
    int lane = threadIdx.x & 63;
    const float4* h4 = (const float4*)hidden;
    if (wave < L) {
        int l = wave;
        const float4* emb4 = (const float4*)(emb_table + (size_t)input[0] * E);
        const float4* w4 = (const float4*)(attn_W + (size_t)l * (E + H));
        float acc = 0.f;
        for (int i = lane; i < (E + H) / 4; i += 64) {
            float4 a = (i < E / 4) ? emb4[i] : h4[i - E / 4];
            float4 b = w4[i];
            acc += a.x * b.x + a.y * b.y + a.z * b.z + a.w * b.w;
        }
        for (int off = 32; off > 0; off >>= 1) acc += __shfl_down(acc, off, 64);
        if (lane == 0) ws[WS_S + l] = acc + attn_b[l];
    } else {
        int k = wave - L;
        if (k < 3 * H) {
            const float4* w4 = (const float4*)(W_hh + (size_t)k * H);
            float acc = 0.f;
            for (int i = lane; i < H / 4; i += 64) {
                float4 a = h4[i];
                float4 b = w4[i];
                acc += a.x * b.x + a.y * b.y + a.z * b.z + a.w * b.w;
            }
            for (int off = 32; off > 0; off >>= 1) acc += __shfl_down(acc, off, 64);
            if (lane == 0) ws[WS_GH + k] = acc + b_hh[k];
        }
    }
}

// K2: softmax over 512 scores (1 block, 512 threads); also stage x[0:E]=emb, zero x[E:E+H]
__global__ void k2_softmax(const int* __restrict__ input,
                           const float* __restrict__ emb_table,
                           float* __restrict__ ws, float* __restrict__ out) {
    __shared__ float red[8];
    __shared__ float bmax, bsum;
    int t = threadIdx.x;
    int lane = t & 63, wid = t >> 6;
    float v = ws[WS_S + t];
    float m = v;
    for (int off = 32; off > 0; off >>= 1) m = fmaxf(m, __shfl_down(m, off, 64));
    if (lane == 0) red[wid] = m;
    __syncthreads();
    if (t == 0) {
        float mm = red[0];
        for (int i = 1; i < 8; i++) mm = fmaxf(mm, red[i]);
        bmax = mm;
    }
    __syncthreads();
    float e = expf(v - bmax);
    float s = e;
    for (int off = 32; off > 0; off >>= 1) s += __shfl_down(s, off, 64);
    if (lane == 0) red[wid] = s;
    __syncthreads();
    if (t == 0) {
        float ss = 0.f;
        for (int i = 0; i < 8; i++) ss += red[i];
        bsum = ss;
    }
    __syncthreads();
    float w = e / bsum;
    ws[WS_W + t] = w;
    out[OUT_AW + t] = w;
    // stage x
    const float* emb = emb_table + (size_t)input[0] * E;
    ws[WS_X + t] = emb[t];
    ws[WS_X + 512 + t] = emb[512 + t];
    ws[WS_X + E + t] = 0.f;
    ws[WS_X + E + 512 + t] = 0.f;
}

// K3: attn_applied[j] += sum over l-chunk of w[l]*enc[l][j]; 32 blocks (4 j-chunks x 8 l-chunks)
__global__ void k3_applied(const float* __restrict__ enc, float* __restrict__ ws) {
    int jc = blockIdx.x & 3, lc = blockIdx.x >> 2;
    int j = jc * 256 + threadIdx.x;
    int l0 = lc * 64;
    float acc = 0.f;
    for (int l = l0; l < l0 + 64; ++l)
        acc += ws[WS_W + l] * enc[(size_t)l * H + j];
    atomicAdd(&ws[WS_X + E + j], acc);
}

// K4: gi = x @ W_ih^T + b_ih; one wave per row, 3072 waves
__global__ void k4_gi(const float* __restrict__ W_ih, const float* __restrict__ b_ih,
                      float* __restrict__ ws) {
    int wave = (blockIdx.x * blockDim.x + threadIdx.x) >> 6;
    int lane = threadIdx.x & 63;
    if (wave >= 3 * H) return;
    const float4* x4 = (const float4*)(ws + WS_X);
    const float4* w4 = (const float4*)(W_ih + (size_t)wave * (E + H));
    float acc = 0.f;
    for (int i = lane; i < (E + H) / 4; i += 64) {
        float4 a = x4[i];
        float4 b = w4[i];
        acc += a.x * b.x + a.y * b.y + a.z * b.z + a.w * b.w;
    }
    for (int off = 32; off > 0; off >>= 1) acc += __shfl_down(acc, off, 64);
    if (lane == 0) ws[WS_GI + wave] = acc + b_ih[wave];
}

// K5: GRU gate combine -> h_new; init sum scratch
__global__ void k5_combine(const float* __restrict__ hidden, float* __restrict__ ws,
                           float* __restrict__ out) {
    int k = blockIdx.x * 256 + threadIdx.x;
    float gir = ws[WS_GI + k],         ghr = ws[WS_GH + k];
    float giz = ws[WS_GI + H + k],     ghz = ws[WS_GH + H + k];
    float gin = ws[WS_GI + 2 * H + k], ghn = ws[WS_GH + 2 * H + k];
    float r = 1.f / (1.f + expf(-(gir + ghr)));
    float z = 1.f / (1.f + expf(-(giz + ghz)));
    float n = tanhf(gin + r * ghn);
    float hn = (1.f - z) * n + z * hidden[k];
    ws[WS_HN + k] = hn;
    out[OUT_H + k] = hn;
    if (k == 0) ws[WS_SUM] = 0.f;
}

// K6: logits = h_new @ out_W^T + out_b; one wave per row, grid-stride; per-block max
__global__ void k6_logits(const float* __restrict__ out_W, const float* __restrict__ out_b,
                          float* __restrict__ ws, float* __restrict__ out) {
    __shared__ float hn[H];
    __shared__ float wmax[4];
    int t = threadIdx.x;
    for (int i = t; i < H; i += 256) hn[i] = ws[WS_HN + i];
    __syncthreads();
    int lane = t & 63, wid = t >> 6;
    int gwave = blockIdx.x * 4 + wid;
    float lmax = -INFINITY;
    const float4* h4 = (const float4*)hn;
    for (int row = gwave; row < V; row += 8192) {
        const float4* w4 = (const float4*)(out_W + (size_t)row * H);
        float acc = 0.f;
        for (int i = lane; i < H / 4; i += 64) {
            float4 a = h4[i];
            float4 b = w4[i];
            acc += a.x * b.x + a.y * b.y + a.z * b.z + a.w * b.w;
        }
        for (int off = 32; off > 0; off >>= 1) acc += __shfl_down(acc, off, 64);
        if (lane == 0) {
            float lg = acc + out_b[row];
            out[OUT_LP + row] = lg;
            lmax = fmaxf(lmax, lg);
        }
    }
    if (lane == 0) wmax[wid] = lmax;
    __syncthreads();
    if (t == 0) {
        float m = fmaxf(fmaxf(wmax[0], wmax[1]), fmaxf(wmax[2], wmax[3]));
        ws[WS_BMAX + blockIdx.x] = m;
    }
}

// K7: global max from block maxes, then sum of exp(logit - max), atomicAdd
__global__ void k7_sumexp(float* __restrict__ ws, const float* __restrict__ out) {
    __shared__ float red[4];
    __shared__ float gmax;
    int t = threadIdx.x;
    int lane = t & 63, wid = t >> 6;
    float m = -INFINITY;
    for (int i = t; i < 2048; i += 256) m = fmaxf(m, ws[WS_BMAX + i]);
    for (int off = 32; off > 0; off >>= 1) m = fmaxf(m, __shfl_down(m, off, 64));
    if (lane == 0) red[wid] = m;
    __syncthreads();
    if (t == 0) gmax = fmaxf(fmaxf(red[0], red[1]), fmaxf(red[2], red[3]));
    __syncthreads();
    float M = gmax;
    float s = 0.f;
    for (int i = blockIdx.x * 256 + t; i < V; i += 64 * 256) s += expf(out[i] - M);
    for (int off = 32; off > 0; off >>= 1) s += __shfl_down(s, off, 64);
    if (lane == 0) red[wid] = s;
    __syncthreads();
    if (t == 0) {
        float bs = red[0] + red[1] + red[2] + red[3];
        atomicAdd(&ws[WS_SUM], bs);
        if (blockIdx.x == 0) ws[WS_MAX] = M;
    }
}

// K8: log_probs = logit - max - log(sum), in place
__global__ void k8_logprobs(const float* __restrict__ ws, float* __restrict__ out) {
    int i = blockIdx.x * 256 + threadIdx.x;
    if (i < V) out[i] = out[i] - ws[WS_MAX] - logf(ws[WS_SUM]);
}

extern "C" void kernel_launch(void* const* d_in, const int* in_sizes, int n_in,
                              void* d_out, int out_size, void* d_ws, size_t ws_size,
                              hipStream_t stream) {
    const int*   input   = (const int*)d_in[0];
    const float* hidden  = (const float*)d_in[1];
    const float* enc     = (const float*)d_in[2];
    const float* emb     = (const float*)d_in[3];
    const float* attn_W  = (const float*)d_in[4];
    const float* attn_b  = (const float*)d_in[5];
    const float* W_ih    = (const float*)d_in[6];
    const float* W_hh    = (const float*)d_in[7];
    const float* b_ih    = (const float*)d_in[8];
    const float* b_hh    = (const float*)d_in[9];
    const float* out_W   = (const float*)d_in[10];
    const float* out_b   = (const float*)d_in[11];
    float* out = (float*)d_out;
    float* ws  = (float*)d_ws;

    k1_scores_gh<<<896, 256, 0, stream>>>(input, hidden, emb, attn_W, attn_b, W_hh, b_hh, ws);
    k2_softmax<<<1, 512, 0, stream>>>(input, emb, ws, out);
    k3_applied<<<32, 256, 0, stream>>>(enc, ws);
    k4_gi<<<768, 256, 0, stream>>>(W_ih, b_ih, ws);
    k5_combine<<<4, 256, 0, stream>>>(hidden, ws, out);
    k6_logits<<<2048, 256, 0, stream>>>(out_W, out_b, ws, out);
    k7_sumexp<<<64, 256, 0, stream>>>(ws, out);
    k8_logprobs<<<197, 256, 0, stream>>>(ws, out);
}